// Round 1
// baseline (127.542 us; speedup 1.0000x reference)
//
#include <hip/hip_runtime.h>
#include <math.h>

constexpr int cB = 8, cN = 1600, cT = 64, cH = 32, cHEADS = 4, cHD = 8, cFC = 16, cHOR = 12;
constexpr int cROWS = cB * cN; // 12800

__device__ __forceinline__ float sigmoidf_(float x) { return 1.0f / (1.0f + __expf(-x)); }
__device__ __forceinline__ float tanhf_(float x) {
    float xc = fminf(fmaxf(x, -15.0f), 15.0f);
    float e = __expf(-2.0f * xc);
    return (1.0f - e) / (1.0f + e);
}

// K0: transpose fp_w (32,1024) -> wT[ct*32+h] so hot loop reads contiguous uniform floats
__global__ __launch_bounds__(256) void k0_transpose(const float* __restrict__ fp_w,
                                                    float* __restrict__ wT) {
    int i = blockIdx.x * 256 + threadIdx.x;   // 0..32767, coalesced read
    int h = i >> 10, ct = i & 1023;
    wT[ct * cH + h] = fp_w[i];
}

// K1: fused depthwise-conv3 + BN1 + ReLU + pointwise(1->16)+BN2+ReLU + feat GEMM.
// Block = 512 threads = 8 waves; each wave handles the same 64 rows, 1/8 of ct (2 channels).
__global__ __launch_bounds__(512) void k1_feat(
    const float* __restrict__ x,
    const float* __restrict__ dw_w, const float* __restrict__ dw_b,
    const float* __restrict__ bn1_g, const float* __restrict__ bn1_b,
    const float* __restrict__ bn1_m, const float* __restrict__ bn1_v,
    const float* __restrict__ pw_w, const float* __restrict__ pw_b,
    const float* __restrict__ bn2_g, const float* __restrict__ bn2_b,
    const float* __restrict__ bn2_m, const float* __restrict__ bn2_v,
    const float* __restrict__ wT, const float* __restrict__ fp_b,
    float* __restrict__ feat_t)
{
    __shared__ float red[4 * cH * 64]; // [w<4][h][lane] = 32KB

    const int tid = threadIdx.x;
    const int lane = tid & 63;
    const int w = __builtin_amdgcn_readfirstlane(tid >> 6); // wave id 0..7, uniform
    const int r0 = blockIdx.x * 64;
    const int row = r0 + lane;
    const int b = r0 / cN;                 // uniform (64 | 1600)
    const int n = row - b * cN;
    const float* xb = x + (size_t)b * cT * cN + n;  // x[b,t,n] = xb[t*cN]

    const float inv1 = bn1_g[0] * rsqrtf(bn1_v[0] + 1e-5f);
    const float A = inv1;
    const float C = (dw_b[0] - bn1_m[0]) * inv1 + bn1_b[0];
    const float w0 = dw_w[0], w1 = dw_w[1], w2 = dw_w[2];

    float y1[cT];
    float xm = 0.0f, xc = xb[0];
    #pragma unroll
    for (int t = 0; t < cT; ++t) {
        float xp = (t + 1 < cT) ? xb[(size_t)(t + 1) * cN] : 0.0f;
        float s = w0 * xm + w1 * xc + w2 * xp;
        y1[t] = fmaxf(0.0f, fmaf(s, A, C));
        xm = xc; xc = xp;
    }

    float acc[cH];
    #pragma unroll
    for (int h = 0; h < cH; ++h) acc[h] = 0.0f;

    #pragma unroll
    for (int cc = 0; cc < 2; ++cc) {
        const int c = 2 * w + cc;  // uniform
        const float inv2 = bn2_g[c] * rsqrtf(bn2_v[c] + 1e-5f);
        const float a2 = pw_w[c] * inv2;
        const float c2 = (pw_b[c] - bn2_m[c]) * inv2 + bn2_b[c];
        const float* wrow = wT + (size_t)(c * cT) * cH;
        #pragma unroll
        for (int t = 0; t < cT; ++t) {
            const float y2 = fmaxf(0.0f, fmaf(a2, y1[t], c2));
            #pragma unroll
            for (int h = 0; h < cH; ++h)
                acc[h] = fmaf(y2, wrow[t * cH + h], acc[h]);
        }
    }

    // two-round cross-wave reduction in 32KB LDS
    if (w < 4) {
        #pragma unroll
        for (int h = 0; h < cH; ++h) red[(w * cH + h) * 64 + lane] = acc[h];
    }
    __syncthreads();
    if (w >= 4) {
        #pragma unroll
        for (int h = 0; h < cH; ++h) red[((w - 4) * cH + h) * 64 + lane] += acc[h];
    }
    __syncthreads();
    for (int o = tid; o < cH * 64; o += 512) {
        float s = red[o] + red[2048 + o] + red[4096 + o] + red[6144 + o];
        int h = o >> 6;
        feat_t[(size_t)h * cROWS + r0 + (o & 63)] = s + fp_b[h];
    }
}

// K2: feat -> qkv (two small matvecs), elu+1, z denom; store qe (row-major), ke/vv (head-major)
__global__ __launch_bounds__(256) void k2_qkv(
    const float* __restrict__ feat_t,
    const float* __restrict__ lo_w, const float* __restrict__ lo_b,
    const float* __restrict__ hi_w, const float* __restrict__ hi_b,
    float* __restrict__ qe, float* __restrict__ keh,
    float* __restrict__ vvh, float* __restrict__ zz)
{
    const int row = blockIdx.x * 256 + threadIdx.x;
    const int b = row / cN;
    const int n = row - b * cN;

    float f[cH];
    #pragma unroll
    for (int i = 0; i < cH; ++i) f[i] = feat_t[(size_t)i * cROWS + row];

    float lo[24];
    #pragma unroll
    for (int j = 0; j < 24; ++j) {
        float s = lo_b[j];
        #pragma unroll
        for (int i = 0; i < cH; ++i) s = fmaf(f[i], lo_w[j * cH + i], s);
        lo[j] = s;
    }

    float t32[32];
    // q -> qe
    #pragma unroll
    for (int j = 0; j < 32; ++j) {
        float s = hi_b[j];
        #pragma unroll
        for (int i = 0; i < 24; ++i) s = fmaf(lo[i], hi_w[j * 24 + i], s);
        t32[j] = (s > 0.0f) ? (s + 1.0f) : __expf(s);
    }
    float* qrow = qe + (size_t)row * 32;
    #pragma unroll
    for (int j = 0; j < 32; ++j) qrow[j] = t32[j];

    // k -> ke (head-major) + z
    #pragma unroll
    for (int j = 0; j < 32; ++j) {
        float s = hi_b[32 + j];
        #pragma unroll
        for (int i = 0; i < 24; ++i) s = fmaf(lo[i], hi_w[(32 + j) * 24 + i], s);
        t32[j] = (s > 0.0f) ? (s + 1.0f) : __expf(s);
    }
    #pragma unroll
    for (int h = 0; h < cHEADS; ++h) {
        float ssum = 1e-8f;
        #pragma unroll
        for (int d = 0; d < cHD; ++d) ssum += t32[h * 8 + d];
        zz[(size_t)(b * cHEADS + h) * cN + n] = 1.0f / ssum;
        float* kp = keh + ((size_t)(b * cHEADS + h) * cN + n) * 8;
        #pragma unroll
        for (int d = 0; d < cHD; ++d) kp[d] = t32[h * 8 + d];
    }

    // v (head-major)
    #pragma unroll
    for (int j = 0; j < 32; ++j) {
        float s = hi_b[64 + j];
        #pragma unroll
        for (int i = 0; i < 24; ++i) s = fmaf(lo[i], hi_w[(64 + j) * 24 + i], s);
        t32[j] = s;
    }
    #pragma unroll
    for (int h = 0; h < cHEADS; ++h) {
        float* vp = vvh + ((size_t)(b * cHEADS + h) * cN + n) * 8;
        #pragma unroll
        for (int d = 0; d < cHD; ++d) vp[d] = t32[h * 8 + d];
    }
}

// K3: kv[b,h,d,e] = sum_n ke[n,d]*vv[n,e] ; one block per (b,h)
__global__ __launch_bounds__(256) void k3_kv(
    const float* __restrict__ keh, const float* __restrict__ vvh,
    float* __restrict__ kv)
{
    const int bh = blockIdx.x;  // 0..31
    const int tid = threadIdx.x;
    const float* kp = keh + (size_t)bh * cN * 8;
    const float* vp = vvh + (size_t)bh * cN * 8;

    float acc[64];
    #pragma unroll
    for (int i = 0; i < 64; ++i) acc[i] = 0.0f;

    for (int n = tid; n < cN; n += 256) {
        const float4* k4 = (const float4*)(kp + (size_t)n * 8);
        const float4* v4 = (const float4*)(vp + (size_t)n * 8);
        float4 ka = k4[0], kb = k4[1], va = v4[0], vb = v4[1];
        float ke8[8] = {ka.x, ka.y, ka.z, ka.w, kb.x, kb.y, kb.z, kb.w};
        float vv8[8] = {va.x, va.y, va.z, va.w, vb.x, vb.y, vb.z, vb.w};
        #pragma unroll
        for (int d = 0; d < 8; ++d)
            #pragma unroll
            for (int e = 0; e < 8; ++e)
                acc[d * 8 + e] = fmaf(ke8[d], vv8[e], acc[d * 8 + e]);
    }

    // wave butterfly reduce, then cross-wave via LDS
    #pragma unroll
    for (int i = 0; i < 64; ++i) {
        float s = acc[i];
        #pragma unroll
        for (int off = 32; off > 0; off >>= 1) s += __shfl_down(s, off);
        acc[i] = s;
    }
    __shared__ float red[4][64];
    const int wv = tid >> 6, ln = tid & 63;
    if (ln == 0) {
        #pragma unroll
        for (int i = 0; i < 64; ++i) red[wv][i] = acc[i];
    }
    __syncthreads();
    if (tid < 64)
        kv[(size_t)bh * 64 + tid] = red[0][tid] + red[1][tid] + red[2][tid] + red[3][tid];
}

// K4: att_out + out proj + feat update + h0 + gate + GRU(12 steps) + final blend + reg
__global__ __launch_bounds__(256) void k4_final(
    const float* __restrict__ x,
    const float* __restrict__ feat_t, const float* __restrict__ qe,
    const float* __restrict__ zz, const float* __restrict__ kv,
    const float* __restrict__ out_lo_w, const float* __restrict__ out_lo_b,
    const float* __restrict__ out_hi_w, const float* __restrict__ out_hi_b,
    const float* __restrict__ hp_w, const float* __restrict__ hp_b,
    const float* __restrict__ gru_wih, const float* __restrict__ gru_whh,
    const float* __restrict__ gru_bih, const float* __restrict__ gru_bhh,
    const float* __restrict__ op_w, const float* __restrict__ op_b,
    const float* __restrict__ log_decay,
    const float* __restrict__ rg1_w, const float* __restrict__ rg1_b,
    const float* __restrict__ rg2_w, const float* __restrict__ rg2_b,
    const float* __restrict__ log_reg,
    float* __restrict__ out)
{
    const int row = blockIdx.x * 256 + threadIdx.x;
    const int b = __builtin_amdgcn_readfirstlane(row / cN); // uniform per wave (64|1600)
    const int n = row - b * cN;

    float qe_r[32];
    const float* qrow = qe + (size_t)row * 32;
    #pragma unroll
    for (int i = 0; i < 32; ++i) qe_r[i] = qrow[i];

    float o[32];
    #pragma unroll
    for (int h = 0; h < cHEADS; ++h) {
        const float z = zz[(size_t)(b * cHEADS + h) * cN + n];
        const float* kvp = kv + (size_t)(b * cHEADS + h) * 64;
        #pragma unroll
        for (int e = 0; e < 8; ++e) {
            float s = 0.0f;
            #pragma unroll
            for (int d = 0; d < 8; ++d) s = fmaf(qe_r[h * 8 + d], kvp[d * 8 + e], s);
            o[h * 8 + e] = s * z;
        }
    }

    float lo[8];
    #pragma unroll
    for (int j = 0; j < 8; ++j) {
        float s = out_lo_b[j];
        #pragma unroll
        for (int i = 0; i < 32; ++i) s = fmaf(o[i], out_lo_w[j * 32 + i], s);
        lo[j] = s;
    }
    float feat2[32];
    #pragma unroll
    for (int i = 0; i < 32; ++i) {
        float s = out_hi_b[i];
        #pragma unroll
        for (int j = 0; j < 8; ++j) s = fmaf(lo[j], out_hi_w[i * 8 + j], s);
        feat2[i] = feat_t[(size_t)i * cROWS + row] + s;
    }

    float h0[8], g1[8];
    #pragma unroll
    for (int j = 0; j < 8; ++j) {
        float s = hp_b[j];
        #pragma unroll
        for (int i = 0; i < 32; ++i) s = fmaf(feat2[i], hp_w[j * 32 + i], s);
        h0[j] = s;
        float g = rg1_b[j];
        #pragma unroll
        for (int i = 0; i < 32; ++i) g = fmaf(feat2[i], rg1_w[j * 32 + i], g);
        g1[j] = fmaxf(0.0f, g);
    }
    float gate[12];
    #pragma unroll
    for (int k = 0; k < 12; ++k) {
        float s = rg2_b[k];
        #pragma unroll
        for (int j = 0; j < 8; ++j) s = fmaf(g1[j], rg2_w[k * 8 + j], s);
        gate[k] = sigmoidf_(s);
    }

    const float last = x[(size_t)b * cT * cN + (size_t)(cT - 1) * cN + n];

    float h[8];
    #pragma unroll
    for (int j = 0; j < 8; ++j) h[j] = h0[j];
    float cur = last;
    float preds[12];
    for (int s = 0; s < 12; ++s) {
        float gh[24];
        #pragma unroll
        for (int j = 0; j < 24; ++j) {
            float t = gru_bhh[j];
            #pragma unroll
            for (int i = 0; i < 8; ++i) t = fmaf(h[i], gru_whh[j * 8 + i], t);
            gh[j] = t;
        }
        float hn[8];
        #pragma unroll
        for (int j = 0; j < 8; ++j) {
            float gx_r = fmaf(gru_wih[j], cur, gru_bih[j]);
            float gx_z = fmaf(gru_wih[8 + j], cur, gru_bih[8 + j]);
            float gx_n = fmaf(gru_wih[16 + j], cur, gru_bih[16 + j]);
            float r = sigmoidf_(gx_r + gh[j]);
            float zg = sigmoidf_(gx_z + gh[8 + j]);
            float nn = tanhf_(gx_n + r * gh[16 + j]);
            hn[j] = (1.0f - zg) * nn + zg * h[j];
        }
        float p = op_b[0];
        #pragma unroll
        for (int j = 0; j < 8; ++j) { p = fmaf(hn[j], op_w[j], p); h[j] = hn[j]; }
        preds[s] = p;
        cur = p;
    }

    const float dk = __expf(log_decay[0]);
    float* orow = out + (size_t)row * 12;
    #pragma unroll
    for (int k = 0; k < 12; ++k) {
        float decay = __expf(-dk * (float)(k + 1));
        orow[k] = gate[k] * preds[k] + (1.0f - gate[k]) * last * decay;
    }
    if (row == 0) out[(size_t)cROWS * 12] = __expf(log_reg[0]) * (1.0f / (float)cN);
}

extern "C" void kernel_launch(void* const* d_in, const int* in_sizes, int n_in,
                              void* d_out, int out_size, void* d_ws, size_t ws_size,
                              hipStream_t stream)
{
    const float* x      = (const float*)d_in[0];
    const float* dw_w   = (const float*)d_in[1];
    const float* dw_b   = (const float*)d_in[2];
    const float* bn1_g  = (const float*)d_in[3];
    const float* bn1_b  = (const float*)d_in[4];
    const float* bn1_m  = (const float*)d_in[5];
    const float* bn1_v  = (const float*)d_in[6];
    const float* pw_w   = (const float*)d_in[7];
    const float* pw_b   = (const float*)d_in[8];
    const float* bn2_g  = (const float*)d_in[9];
    const float* bn2_b  = (const float*)d_in[10];
    const float* bn2_m  = (const float*)d_in[11];
    const float* bn2_v  = (const float*)d_in[12];
    const float* fp_w   = (const float*)d_in[13];
    const float* fp_b   = (const float*)d_in[14];
    const float* lo_w   = (const float*)d_in[15];
    const float* lo_b   = (const float*)d_in[16];
    const float* hi_w   = (const float*)d_in[17];
    const float* hi_b   = (const float*)d_in[18];
    const float* olo_w  = (const float*)d_in[19];
    const float* olo_b  = (const float*)d_in[20];
    const float* ohi_w  = (const float*)d_in[21];
    const float* ohi_b  = (const float*)d_in[22];
    // d_in[23]=u, d_in[24]=v are mathematically dead (softmax row-sums == 1)
    const float* log_reg = (const float*)d_in[25];
    const float* hp_w   = (const float*)d_in[26];
    const float* hp_b   = (const float*)d_in[27];
    const float* gru_wih = (const float*)d_in[28];
    const float* gru_whh = (const float*)d_in[29];
    const float* gru_bih = (const float*)d_in[30];
    const float* gru_bhh = (const float*)d_in[31];
    const float* op_w   = (const float*)d_in[32];
    const float* op_b   = (const float*)d_in[33];
    const float* log_decay = (const float*)d_in[34];
    const float* rg1_w  = (const float*)d_in[35];
    const float* rg1_b  = (const float*)d_in[36];
    const float* rg2_w  = (const float*)d_in[37];
    const float* rg2_b  = (const float*)d_in[38];

    float* ws    = (float*)d_ws;
    float* wT    = ws;                    // 32768
    float* feat_t = wT + 32768;           // 409600  [h*12800+row]
    float* qe    = feat_t + 409600;       // 409600  [row*32]
    float* keh   = qe + 409600;           // 409600  [(b*4+h)*1600+n]*8
    float* vvh   = keh + 409600;          // 409600
    float* zz    = vvh + 409600;          // 51200   [(b*4+h)*1600+n]
    float* kv    = zz + 51200;            // 2048

    k0_transpose<<<128, 256, 0, stream>>>(fp_w, wT);
    k1_feat<<<cROWS / 64, 512, 0, stream>>>(x, dw_w, dw_b, bn1_g, bn1_b, bn1_m, bn1_v,
                                            pw_w, pw_b, bn2_g, bn2_b, bn2_m, bn2_v,
                                            wT, fp_b, feat_t);
    k2_qkv<<<cROWS / 256, 256, 0, stream>>>(feat_t, lo_w, lo_b, hi_w, hi_b,
                                            qe, keh, vvh, zz);
    k3_kv<<<cB * cHEADS, 256, 0, stream>>>(keh, vvh, kv);
    k4_final<<<cROWS / 256, 256, 0, stream>>>(x, feat_t, qe, zz, kv,
                                              olo_w, olo_b, ohi_w, ohi_b,
                                              hp_w, hp_b, gru_wih, gru_whh, gru_bih, gru_bhh,
                                              op_w, op_b, log_decay,
                                              rg1_w, rg1_b, rg2_w, rg2_b, log_reg,
                                              (float*)d_out);
}

// Round 2
// 76.014 us; speedup vs baseline: 1.6779x; 1.6779x over previous
//
#include <hip/hip_runtime.h>
#include <math.h>

constexpr int cB = 8, cN = 1600, cT = 64, cH = 32, cHEADS = 4, cHD = 8, cFC = 16, cHOR = 12;
constexpr int cROWS = cB * cN; // 12800

__device__ __forceinline__ float sigmoidf_(float x) { return 1.0f / (1.0f + __expf(-x)); }
__device__ __forceinline__ float tanhf_(float x) {
    float xc = fminf(fmaxf(x, -15.0f), 15.0f);
    float e = __expf(-2.0f * xc);
    return (1.0f - e) / (1.0f + e);
}
__device__ __forceinline__ float elu1_(float x) { return (x > 0.0f) ? (x + 1.0f) : __expf(x); }

// K0: transpose fp_w (32,1024) -> wT[ct*32+h]
__global__ __launch_bounds__(256) void k0_transpose(const float* __restrict__ fp_w,
                                                    float* __restrict__ wT) {
    int i = blockIdx.x * 256 + threadIdx.x;
    int h = i >> 10, ct = i & 1023;
    wT[ct * cH + h] = fp_w[i];
}

// K1: fused conv+BN+ReLU+pointwise+BN+ReLU + feat GEMM. 1024 thr = 16 waves, 1 channel/wave.
__global__ __launch_bounds__(1024) void k1_feat(
    const float* __restrict__ x,
    const float* __restrict__ dw_w, const float* __restrict__ dw_b,
    const float* __restrict__ bn1_g, const float* __restrict__ bn1_b,
    const float* __restrict__ bn1_m, const float* __restrict__ bn1_v,
    const float* __restrict__ pw_w, const float* __restrict__ pw_b,
    const float* __restrict__ bn2_g, const float* __restrict__ bn2_b,
    const float* __restrict__ bn2_m, const float* __restrict__ bn2_v,
    const float* __restrict__ wT, const float* __restrict__ fp_b,
    float* __restrict__ feat_r)
{
    __shared__ float red[8][cH * 65]; // padded: [w][h*65+lane], 66560 B

    const int tid = threadIdx.x;
    const int lane = tid & 63;
    const int w = __builtin_amdgcn_readfirstlane(tid >> 6); // 0..15 = channel
    const int r0 = blockIdx.x * 64;
    const int row = r0 + lane;
    const int b = r0 / cN;
    const int n = row - b * cN;
    const float* xb = x + (size_t)b * cT * cN + n;

    const float inv1 = bn1_g[0] * rsqrtf(bn1_v[0] + 1e-5f);
    const float A = inv1;
    const float C = (dw_b[0] - bn1_m[0]) * inv1 + bn1_b[0];
    const float w0 = dw_w[0], w1 = dw_w[1], w2 = dw_w[2];

    float y1[cT];
    float xm = 0.0f, xc = xb[0];
    #pragma unroll
    for (int t = 0; t < cT; ++t) {
        float xp = (t + 1 < cT) ? xb[(size_t)(t + 1) * cN] : 0.0f;
        float s = w0 * xm + w1 * xc + w2 * xp;
        y1[t] = fmaxf(0.0f, fmaf(s, A, C));
        xm = xc; xc = xp;
    }

    const int c = w;
    const float inv2 = bn2_g[c] * rsqrtf(bn2_v[c] + 1e-5f);
    const float a2 = pw_w[c] * inv2;
    const float c2 = (pw_b[c] - bn2_m[c]) * inv2 + bn2_b[c];
    const float* wrow = wT + (size_t)(c * cT) * cH;

    float acc[cH];
    #pragma unroll
    for (int h = 0; h < cH; ++h) acc[h] = 0.0f;
    #pragma unroll
    for (int t = 0; t < cT; ++t) {
        const float y2 = fmaxf(0.0f, fmaf(a2, y1[t], c2));
        #pragma unroll
        for (int h = 0; h < cH; ++h)
            acc[h] = fmaf(y2, wrow[t * cH + h], acc[h]);
    }

    if (w < 8) {
        #pragma unroll
        for (int h = 0; h < cH; ++h) red[w][h * 65 + lane] = acc[h];
    }
    __syncthreads();
    if (w >= 8) {
        #pragma unroll
        for (int h = 0; h < cH; ++h) red[w - 8][h * 65 + lane] += acc[h];
    }
    __syncthreads();
    if (w < 4) {
        #pragma unroll
        for (int h = 0; h < cH; ++h) red[w][h * 65 + lane] += red[w + 4][h * 65 + lane];
    }
    __syncthreads();
    #pragma unroll
    for (int o2 = 0; o2 < 2; ++o2) {
        int o = tid + o2 * 1024;
        int rp = o >> 5, h = o & 31;
        float s = red[0][h * 65 + rp] + red[1][h * 65 + rp] +
                  red[2][h * 65 + rp] + red[3][h * 65 + rp] + fp_b[h];
        feat_r[(size_t)(r0 + rp) * cH + h] = s;
    }
}

// K2: qkv + elu+1 + z.  8 lanes per row; 256 thr = 32 rows; grid 400.
__global__ __launch_bounds__(256) void k2_qkv(
    const float* __restrict__ feat_r,
    const float* __restrict__ lo_w, const float* __restrict__ lo_b,
    const float* __restrict__ hi_w, const float* __restrict__ hi_b,
    float* __restrict__ qe, float* __restrict__ keh,
    float* __restrict__ vvh, float* __restrict__ zz)
{
    __shared__ float lbuf[32][25];
    const int tid = threadIdx.x;
    const int r = tid >> 3;      // row in block 0..31
    const int j = tid & 7;       // octet lane
    const int row = blockIdx.x * 32 + r;
    const int b = __builtin_amdgcn_readfirstlane(row / cN);
    const int n = row - b * cN;

    float f[cH];
    const float4* fr4 = (const float4*)(feat_r + (size_t)row * cH);
    #pragma unroll
    for (int q = 0; q < 8; ++q) {
        float4 v = fr4[q];
        f[4*q] = v.x; f[4*q+1] = v.y; f[4*q+2] = v.z; f[4*q+3] = v.w;
    }

    float lo0 = lo_b[j], lo1 = lo_b[j+8], lo2 = lo_b[j+16];
    #pragma unroll
    for (int i = 0; i < cH; ++i) {
        lo0 = fmaf(f[i], lo_w[j * cH + i], lo0);
        lo1 = fmaf(f[i], lo_w[(j+8) * cH + i], lo1);
        lo2 = fmaf(f[i], lo_w[(j+16) * cH + i], lo2);
    }
    lbuf[r][j] = lo0; lbuf[r][j+8] = lo1; lbuf[r][j+16] = lo2;
    __syncthreads();
    float lof[24];
    #pragma unroll
    for (int i = 0; i < 24; ++i) lof[i] = lbuf[r][i];

    float qv[4], kv4[4], vv4[4];
    #pragma unroll
    for (int m = 0; m < 4; ++m) {
        const int oi = m * 8 + j;
        float sq = hi_b[oi], sk = hi_b[32 + oi], sv = hi_b[64 + oi];
        #pragma unroll
        for (int i = 0; i < 24; ++i) {
            sq = fmaf(lof[i], hi_w[oi * 24 + i], sq);
            sk = fmaf(lof[i], hi_w[(32 + oi) * 24 + i], sk);
            sv = fmaf(lof[i], hi_w[(64 + oi) * 24 + i], sv);
        }
        qv[m] = elu1_(sq);
        kv4[m] = elu1_(sk);
        vv4[m] = sv;
    }

    // z: per-head sums across octet lanes
    float s0 = kv4[0], s1 = kv4[1], s2 = kv4[2], s3 = kv4[3];
    #pragma unroll
    for (int off = 1; off < 8; off <<= 1) {
        s0 += __shfl_xor(s0, off, 8);
        s1 += __shfl_xor(s1, off, 8);
        s2 += __shfl_xor(s2, off, 8);
        s3 += __shfl_xor(s3, off, 8);
    }
    if (j < 4) {
        float sv = (j == 0) ? s0 : ((j == 1) ? s1 : ((j == 2) ? s2 : s3));
        zz[(size_t)(b * cHEADS + j) * cN + n] = 1.0f / (sv + 1e-8f);
    }

    #pragma unroll
    for (int m = 0; m < 4; ++m) {
        qe[(size_t)row * cH + m * 8 + j] = qv[m];
        keh[((size_t)(b * cHEADS + m) * cN + n) * 8 + j] = kv4[m];
        vvh[((size_t)(b * cHEADS + m) * cN + n) * 8 + j] = vv4[m];
    }
}

// K3: kv[bh][d][e] partial sums; 4 blocks per bh, atomicAdd (kv pre-zeroed).
__global__ __launch_bounds__(256) void k3_kv(
    const float* __restrict__ keh, const float* __restrict__ vvh,
    float* __restrict__ kv)
{
    const int bh = blockIdx.x >> 2;
    const int part = blockIdx.x & 3;
    const int tid = threadIdx.x;
    const float* kp = keh + (size_t)bh * cN * 8;
    const float* vp = vvh + (size_t)bh * cN * 8;

    float acc[64];
    #pragma unroll
    for (int i = 0; i < 64; ++i) acc[i] = 0.0f;

    for (int t = tid; t < 400; t += 256) {
        int n = part * 400 + t;
        const float4* k4 = (const float4*)(kp + (size_t)n * 8);
        const float4* v4 = (const float4*)(vp + (size_t)n * 8);
        float4 ka = k4[0], kb = k4[1], va = v4[0], vb = v4[1];
        float ke8[8] = {ka.x, ka.y, ka.z, ka.w, kb.x, kb.y, kb.z, kb.w};
        float vv8[8] = {va.x, va.y, va.z, va.w, vb.x, vb.y, vb.z, vb.w};
        #pragma unroll
        for (int d = 0; d < 8; ++d)
            #pragma unroll
            for (int e = 0; e < 8; ++e)
                acc[d * 8 + e] = fmaf(ke8[d], vv8[e], acc[d * 8 + e]);
    }

    #pragma unroll
    for (int i = 0; i < 64; ++i) {
        float s = acc[i];
        #pragma unroll
        for (int off = 32; off > 0; off >>= 1) s += __shfl_down(s, off);
        acc[i] = s;
    }
    __shared__ float red[4][64];
    const int wv = tid >> 6, ln = tid & 63;
    if (ln == 0) {
        #pragma unroll
        for (int i = 0; i < 64; ++i) red[wv][i] = acc[i];
    }
    __syncthreads();
    if (tid < 64)
        atomicAdd(&kv[(size_t)bh * 64 + tid],
                  red[0][tid] + red[1][tid] + red[2][tid] + red[3][tid]);
}

// K4: att_out + projections + GRU + blend. 8 lanes/row, 256 thr = 32 rows, grid 400.
__global__ __launch_bounds__(256) void k4_final(
    const float* __restrict__ x,
    const float* __restrict__ feat_r, const float* __restrict__ qe,
    const float* __restrict__ zz, const float* __restrict__ kv,
    const float* __restrict__ out_lo_w, const float* __restrict__ out_lo_b,
    const float* __restrict__ out_hi_w, const float* __restrict__ out_hi_b,
    const float* __restrict__ hp_w, const float* __restrict__ hp_b,
    const float* __restrict__ gru_wih, const float* __restrict__ gru_whh,
    const float* __restrict__ gru_bih, const float* __restrict__ gru_bhh,
    const float* __restrict__ op_w, const float* __restrict__ op_b,
    const float* __restrict__ log_decay,
    const float* __restrict__ rg1_w, const float* __restrict__ rg1_b,
    const float* __restrict__ rg2_w, const float* __restrict__ rg2_b,
    const float* __restrict__ log_reg,
    float* __restrict__ out)
{
    __shared__ float sA[32][36]; // qe rows
    __shared__ float sB[32][36]; // o share
    __shared__ float sC[32][36]; // feat2 share

    const int tid = threadIdx.x;
    const int r = tid >> 3;
    const int j = tid & 7;
    const int row = blockIdx.x * 32 + r;
    const int b = __builtin_amdgcn_readfirstlane(row / cN);
    const int n = row - b * cN;

    // stage qe row into LDS
    {
        const float4* q4 = (const float4*)(qe + (size_t)row * cH);
        float4 v = q4[j];   // lane j loads elements 4j..4j+3 (one octet covers row)
        *(float4*)&sA[r][4 * j] = v;
        // also lanes handle remaining 4 floats: 8 lanes x 4 = 32 ✓
    }
    __syncthreads();

    // att_out: lane j owns o[m*8+j]
    float o_m[4];
    #pragma unroll
    for (int m = 0; m < 4; ++m) {
        const float z = zz[(size_t)(b * cHEADS + m) * cN + n];
        const float* kvp = kv + (size_t)(b * cHEADS + m) * 64;
        float s = 0.0f;
        #pragma unroll
        for (int d = 0; d < 8; ++d)
            s = fmaf(sA[r][m * 8 + d], kvp[d * 8 + j], s);
        o_m[m] = s * z;
    }
    #pragma unroll
    for (int m = 0; m < 4; ++m) sB[r][m * 8 + j] = o_m[m];
    __syncthreads();

    // lo[j] = dot(o, out_lo_w[j])
    float lo_j = out_lo_b[j];
    #pragma unroll
    for (int i = 0; i < cH; ++i)
        lo_j = fmaf(sB[r][i], out_lo_w[j * cH + i], lo_j);

    float lof[8];
    #pragma unroll
    for (int i = 0; i < 8; ++i) lof[i] = __shfl(lo_j, i, 8);

    // feat2 at indices {m*8+j}
    float f2_m[4];
    #pragma unroll
    for (int m = 0; m < 4; ++m) {
        const int i = m * 8 + j;
        float s = out_hi_b[i];
        #pragma unroll
        for (int q = 0; q < 8; ++q) s = fmaf(lof[q], out_hi_w[i * 8 + q], s);
        f2_m[m] = feat_r[(size_t)row * cH + i] + s;
        sC[r][i] = f2_m[m];
    }
    __syncthreads();

    // h0[j], g1[j]
    float h0_j = hp_b[j], g1_j = rg1_b[j];
    #pragma unroll
    for (int i = 0; i < cH; ++i) {
        float fv = sC[r][i];
        h0_j = fmaf(fv, hp_w[j * cH + i], h0_j);
        g1_j = fmaf(fv, rg1_w[j * cH + i], g1_j);
    }
    g1_j = fmaxf(0.0f, g1_j);

    float g1f[8];
    #pragma unroll
    for (int i = 0; i < 8; ++i) g1f[i] = __shfl(g1_j, i, 8);

    float ga = rg2_b[j], gb_ = rg2_b[8 + (j & 3)];
    #pragma unroll
    for (int q = 0; q < 8; ++q) {
        ga = fmaf(g1f[q], rg2_w[j * 8 + q], ga);
        gb_ = fmaf(g1f[q], rg2_w[(8 + (j & 3)) * 8 + q], gb_);
    }
    const float gate_a = sigmoidf_(ga);
    const float gate_b = sigmoidf_(gb_);

    const float last = x[(size_t)b * cT * cN + (size_t)(cT - 1) * cN + n];

    // GRU weights for this lane's j
    float whh_r[8], whh_z[8], whh_n[8], opw[8];
    #pragma unroll
    for (int i = 0; i < 8; ++i) {
        whh_r[i] = gru_whh[j * 8 + i];
        whh_z[i] = gru_whh[(8 + j) * 8 + i];
        whh_n[i] = gru_whh[(16 + j) * 8 + i];
        opw[i] = op_w[i];
    }
    const float wih_r = gru_wih[j], wih_z = gru_wih[8 + j], wih_n = gru_wih[16 + j];
    const float bih_r = gru_bih[j], bih_z = gru_bih[8 + j], bih_n = gru_bih[16 + j];
    const float bhh_r = gru_bhh[j], bhh_z = gru_bhh[8 + j], bhh_n = gru_bhh[16 + j];
    const float opb = op_b[0];

    float h_full[8];
    #pragma unroll
    for (int i = 0; i < 8; ++i) h_full[i] = __shfl(h0_j, i, 8);
    float h_own = h0_j;
    float cur = last;
    float po_a = 0.0f, po_b = 0.0f;

    #pragma unroll
    for (int s = 0; s < cHOR; ++s) {
        float ghr = bhh_r, ghz = bhh_z, ghn = bhh_n;
        #pragma unroll
        for (int i = 0; i < 8; ++i) {
            ghr = fmaf(h_full[i], whh_r[i], ghr);
            ghz = fmaf(h_full[i], whh_z[i], ghz);
            ghn = fmaf(h_full[i], whh_n[i], ghn);
        }
        const float r_ = sigmoidf_(fmaf(wih_r, cur, bih_r) + ghr);
        const float zg = sigmoidf_(fmaf(wih_z, cur, bih_z) + ghz);
        const float nn = tanhf_(fmaf(wih_n, cur, bih_n) + r_ * ghn);
        const float hn = (1.0f - zg) * nn + zg * h_own;
        h_own = hn;
        #pragma unroll
        for (int i = 0; i < 8; ++i) h_full[i] = __shfl(hn, i, 8);
        float p = opb;
        #pragma unroll
        for (int i = 0; i < 8; ++i) p = fmaf(h_full[i], opw[i], p);
        po_a = (s == j) ? p : po_a;
        po_b = (s == 8 + j) ? p : po_b;
        cur = p;
    }

    const float dk = __expf(log_decay[0]);
    float* orow = out + (size_t)row * 12;
    orow[j] = gate_a * po_a + (1.0f - gate_a) * last * __expf(-dk * (float)(j + 1));
    if (j < 4)
        orow[8 + j] = gate_b * po_b + (1.0f - gate_b) * last * __expf(-dk * (float)(j + 9));

    if (row == 0 && j == 0)
        out[(size_t)cROWS * 12] = __expf(log_reg[0]) * (1.0f / (float)cN);
}

extern "C" void kernel_launch(void* const* d_in, const int* in_sizes, int n_in,
                              void* d_out, int out_size, void* d_ws, size_t ws_size,
                              hipStream_t stream)
{
    const float* x      = (const float*)d_in[0];
    const float* dw_w   = (const float*)d_in[1];
    const float* dw_b   = (const float*)d_in[2];
    const float* bn1_g  = (const float*)d_in[3];
    const float* bn1_b  = (const float*)d_in[4];
    const float* bn1_m  = (const float*)d_in[5];
    const float* bn1_v  = (const float*)d_in[6];
    const float* pw_w   = (const float*)d_in[7];
    const float* pw_b   = (const float*)d_in[8];
    const float* bn2_g  = (const float*)d_in[9];
    const float* bn2_b  = (const float*)d_in[10];
    const float* bn2_m  = (const float*)d_in[11];
    const float* bn2_v  = (const float*)d_in[12];
    const float* fp_w   = (const float*)d_in[13];
    const float* fp_b   = (const float*)d_in[14];
    const float* lo_w   = (const float*)d_in[15];
    const float* lo_b   = (const float*)d_in[16];
    const float* hi_w   = (const float*)d_in[17];
    const float* hi_b   = (const float*)d_in[18];
    const float* olo_w  = (const float*)d_in[19];
    const float* olo_b  = (const float*)d_in[20];
    const float* ohi_w  = (const float*)d_in[21];
    const float* ohi_b  = (const float*)d_in[22];
    // d_in[23]=u, d_in[24]=v dead (softmax row-sums == 1 -> mean|attn| == 1/N)
    const float* log_reg = (const float*)d_in[25];
    const float* hp_w   = (const float*)d_in[26];
    const float* hp_b   = (const float*)d_in[27];
    const float* gru_wih = (const float*)d_in[28];
    const float* gru_whh = (const float*)d_in[29];
    const float* gru_bih = (const float*)d_in[30];
    const float* gru_bhh = (const float*)d_in[31];
    const float* op_w   = (const float*)d_in[32];
    const float* op_b   = (const float*)d_in[33];
    const float* log_decay = (const float*)d_in[34];
    const float* rg1_w  = (const float*)d_in[35];
    const float* rg1_b  = (const float*)d_in[36];
    const float* rg2_w  = (const float*)d_in[37];
    const float* rg2_b  = (const float*)d_in[38];

    float* ws     = (float*)d_ws;
    float* wT     = ws;                    // 32768
    float* feat_r = wT + 32768;            // 409600  [row*32+h]
    float* qe     = feat_r + 409600;       // 409600  [row*32]
    float* keh    = qe + 409600;           // 409600  [(bh*1600+n)*8+d]
    float* vvh    = keh + 409600;          // 409600
    float* zz     = vvh + 409600;          // 51200
    float* kv     = zz + 51200;            // 2048

    hipMemsetAsync(kv, 0, cB * cHEADS * 64 * sizeof(float), stream);
    k0_transpose<<<128, 256, 0, stream>>>(fp_w, wT);
    k1_feat<<<cROWS / 64, 1024, 0, stream>>>(x, dw_w, dw_b, bn1_g, bn1_b, bn1_m, bn1_v,
                                             pw_w, pw_b, bn2_g, bn2_b, bn2_m, bn2_v,
                                             wT, fp_b, feat_r);
    k2_qkv<<<cROWS / 32, 256, 0, stream>>>(feat_r, lo_w, lo_b, hi_w, hi_b,
                                           qe, keh, vvh, zz);
    k3_kv<<<cB * cHEADS * 4, 256, 0, stream>>>(keh, vvh, kv);
    k4_final<<<cROWS / 32, 256, 0, stream>>>(x, feat_r, qe, zz, kv,
                                             olo_w, olo_b, ohi_w, ohi_b,
                                             hp_w, hp_b, gru_wih, gru_whh, gru_bih, gru_bhh,
                                             op_w, op_b, log_decay,
                                             rg1_w, rg1_b, rg2_w, rg2_b, log_reg,
                                             (float*)d_out);
}

// Round 3
// 64.719 us; speedup vs baseline: 1.9707x; 1.1745x over previous
//
#include <hip/hip_runtime.h>
#include <math.h>

constexpr int cB = 8, cN = 1600, cT = 64, cH = 32, cHEADS = 4, cHD = 8, cFC = 16, cHOR = 12;
constexpr int cROWS = cB * cN; // 12800

__device__ __forceinline__ float sigmoidf_(float x) { return 1.0f / (1.0f + __expf(-x)); }
__device__ __forceinline__ float tanhf_(float x) {
    float xc = fminf(fmaxf(x, -15.0f), 15.0f);
    float e = __expf(-2.0f * xc);
    return (1.0f - e) / (1.0f + e);
}
__device__ __forceinline__ float elu1_(float x) { return (x > 0.0f) ? (x + 1.0f) : __expf(x); }

// K0: transpose fp_w (32,1024) -> wT[ct*32+h]; also zero kv accumulator (replaces memset)
__global__ __launch_bounds__(256) void k0_init(const float* __restrict__ fp_w,
                                               float* __restrict__ wT,
                                               float* __restrict__ kv) {
    int i = blockIdx.x * 256 + threadIdx.x;
    int h = i >> 10, ct = i & 1023;
    wT[ct * cH + h] = fp_w[i];
    if (i < cB * cHEADS * 64) kv[i] = 0.0f;
}

// kA: conv+BN+ReLU+pointwise+BN+ReLU+feat GEMM, then qkv+elu+z, then partial kv
// outer-product reduction — all in one block per 64 rows. 1024 thr = 16 waves.
__global__ __launch_bounds__(1024) void kA(
    const float* __restrict__ x,
    const float* __restrict__ dw_w, const float* __restrict__ dw_b,
    const float* __restrict__ bn1_g, const float* __restrict__ bn1_b,
    const float* __restrict__ bn1_m, const float* __restrict__ bn1_v,
    const float* __restrict__ pw_w, const float* __restrict__ pw_b,
    const float* __restrict__ bn2_g, const float* __restrict__ bn2_b,
    const float* __restrict__ bn2_m, const float* __restrict__ bn2_v,
    const float* __restrict__ wT, const float* __restrict__ fp_b,
    const float* __restrict__ lo_w, const float* __restrict__ lo_b,
    const float* __restrict__ hi_w, const float* __restrict__ hi_b,
    float* __restrict__ feat_r, float* __restrict__ qe,
    float* __restrict__ zz, float* __restrict__ kvout)
{
    // phase1: lds_[w*2080 + h*65 + lane], 8 slots = 16640 floats = 66560 B
    // phase2 aliases slots 4..7 (offset 8320):
    //   sfeat @8320 (64*33=2112), lbuf @10432 (64*25=1600, pkv aliases),
    //   skv @12032 (2048), svv @14080 (2048)
    __shared__ float lds_[16640];

    const int tid = threadIdx.x;
    const int lane = tid & 63;
    const int w = __builtin_amdgcn_readfirstlane(tid >> 6); // 0..15 = channel
    const int r0 = blockIdx.x * 64;
    const int b = r0 / cN;          // uniform; 64 | 1600 so blocks don't straddle b
    const int n0 = r0 - b * cN;
    const float* xb = x + (size_t)b * cT * cN + (n0 + lane);

    // ---- phase 1: depthwise conv + BN1 + ReLU ----
    const float inv1 = bn1_g[0] * rsqrtf(bn1_v[0] + 1e-5f);
    const float A = inv1;
    const float C = (dw_b[0] - bn1_m[0]) * inv1 + bn1_b[0];
    const float w0 = dw_w[0], w1 = dw_w[1], w2 = dw_w[2];

    float y1[cT];
    float xm = 0.0f, xc = xb[0];
    #pragma unroll
    for (int t = 0; t < cT; ++t) {
        float xp = (t + 1 < cT) ? xb[(size_t)(t + 1) * cN] : 0.0f;
        float s = w0 * xm + w1 * xc + w2 * xp;
        y1[t] = fmaxf(0.0f, fmaf(s, A, C));
        xm = xc; xc = xp;
    }

    // pointwise channel w + BN2 + ReLU + GEMM slice
    const int c = w;
    const float inv2 = bn2_g[c] * rsqrtf(bn2_v[c] + 1e-5f);
    const float a2 = pw_w[c] * inv2;
    const float c2 = (pw_b[c] - bn2_m[c]) * inv2 + bn2_b[c];
    const float* wrow = wT + (size_t)(c * cT) * cH;

    float acc[cH];
    #pragma unroll
    for (int h = 0; h < cH; ++h) acc[h] = 0.0f;
    #pragma unroll
    for (int t = 0; t < cT; ++t) {
        const float y2 = fmaxf(0.0f, fmaf(a2, y1[t], c2));
        #pragma unroll
        for (int h = 0; h < cH; ++h)
            acc[h] = fmaf(y2, wrow[t * cH + h], acc[h]);
    }

    if (w < 8) {
        #pragma unroll
        for (int h = 0; h < cH; ++h) lds_[w * 2080 + h * 65 + lane] = acc[h];
    }
    __syncthreads();
    if (w >= 8) {
        #pragma unroll
        for (int h = 0; h < cH; ++h) lds_[(w - 8) * 2080 + h * 65 + lane] += acc[h];
    }
    __syncthreads();
    if (w < 4) {
        #pragma unroll
        for (int h = 0; h < cH; ++h) lds_[w * 2080 + h * 65 + lane] += lds_[(w + 4) * 2080 + h * 65 + lane];
    }
    __syncthreads();

    float* sfeat = lds_ + 8320;
    float* lbuf  = lds_ + 10432;
    float* skv   = lds_ + 12032;
    float* svv   = lds_ + 14080;
    float* pkv   = lds_ + 10432; // aliases lbuf (done by then)

    // ---- final feat: write global + LDS ----
    #pragma unroll
    for (int o2 = 0; o2 < 2; ++o2) {
        int o = tid + o2 * 1024;
        int rp = o >> 5, h = o & 31;
        float s = lds_[0 * 2080 + h * 65 + rp] + lds_[1 * 2080 + h * 65 + rp] +
                  lds_[2 * 2080 + h * 65 + rp] + lds_[3 * 2080 + h * 65 + rp] + fp_b[h];
        feat_r[(size_t)(r0 + rp) * cH + h] = s;
        sfeat[rp * 33 + h] = s;
    }
    __syncthreads();

    const int r = tid >> 4;   // 0..63 row in block
    const int l = tid & 15;   // 16 lanes per row
    const int row = r0 + r;
    const int n = n0 + r;

    // ---- lo = qkv_lo(feat) : 24 outputs/row ----
    {
        float f[cH];
        #pragma unroll
        for (int i = 0; i < cH; ++i) f[i] = sfeat[r * 33 + i];
        float lo0 = lo_b[l];
        #pragma unroll
        for (int i = 0; i < cH; ++i) lo0 = fmaf(f[i], lo_w[l * cH + i], lo0);
        lbuf[r * 25 + l] = lo0;
        if (l < 8) {
            float lo1 = lo_b[16 + l];
            #pragma unroll
            for (int i = 0; i < cH; ++i) lo1 = fmaf(f[i], lo_w[(16 + l) * cH + i], lo1);
            lbuf[r * 25 + 16 + l] = lo1;
        }
    }
    __syncthreads();

    // ---- qkv_hi + elu + z ----
    {
        float lof[24];
        #pragma unroll
        for (int i = 0; i < 24; ++i) lof[i] = lbuf[r * 25 + i];

        const int i0 = l, i1 = l + 16;
        float sq0 = hi_b[i0], sq1 = hi_b[i1];
        float sk0 = hi_b[32 + i0], sk1 = hi_b[32 + i1];
        float sv0 = hi_b[64 + i0], sv1 = hi_b[64 + i1];
        #pragma unroll
        for (int i = 0; i < 24; ++i) {
            const float lv = lof[i];
            sq0 = fmaf(lv, hi_w[i0 * 24 + i], sq0);
            sq1 = fmaf(lv, hi_w[i1 * 24 + i], sq1);
            sk0 = fmaf(lv, hi_w[(32 + i0) * 24 + i], sk0);
            sk1 = fmaf(lv, hi_w[(32 + i1) * 24 + i], sk1);
            sv0 = fmaf(lv, hi_w[(64 + i0) * 24 + i], sv0);
            sv1 = fmaf(lv, hi_w[(64 + i1) * 24 + i], sv1);
        }
        const float q0 = elu1_(sq0), q1 = elu1_(sq1);
        const float k0 = elu1_(sk0), k1e = elu1_(sk1);

        qe[(size_t)row * cH + i0] = q0;
        qe[(size_t)row * cH + i1] = q1;
        skv[r * 32 + i0] = k0;  skv[r * 32 + i1] = k1e;
        svv[r * 32 + i0] = sv0; svv[r * 32 + i1] = sv1;

        // z: sum ke over each head (8 consecutive indices) via 8-lane butterflies
        float s_lo = k0, s_hi = k1e;
        #pragma unroll
        for (int off = 1; off < 8; off <<= 1) {
            s_lo += __shfl_xor(s_lo, off, 8);
            s_hi += __shfl_xor(s_hi, off, 8);
        }
        if ((l & 7) == 0) {
            const int hA = l >> 3;       // 0 or 1
            zz[(size_t)(b * cHEADS + hA) * cN + n]     = 1.0f / (s_lo + 1e-8f);
            zz[(size_t)(b * cHEADS + 2 + hA) * cN + n] = 1.0f / (s_hi + 1e-8f);
        }
    }
    __syncthreads();

    // ---- partial kv: 256 (head,d,e) combos x 4 row-groups ----
    {
        const int combo = tid & 255, grp = tid >> 8;
        const int hh = combo >> 6, d = (combo >> 3) & 7, e = combo & 7;
        float s = 0.0f;
        #pragma unroll
        for (int rr = 0; rr < 16; ++rr) {
            const int ri = grp * 16 + rr;
            s = fmaf(skv[ri * 32 + hh * 8 + d], svv[ri * 32 + hh * 8 + e], s);
        }
        pkv[grp * 256 + combo] = s;
    }
    __syncthreads();
    if (tid < 256) {
        float s = pkv[tid] + pkv[256 + tid] + pkv[512 + tid] + pkv[768 + tid];
        atomicAdd(&kvout[(size_t)(b * cHEADS + (tid >> 6)) * 64 + (tid & 63)], s);
    }
}

// K4: att_out + projections + GRU + blend. 8 lanes/row, 256 thr = 32 rows, grid 400.
__global__ __launch_bounds__(256) void k4_final(
    const float* __restrict__ x,
    const float* __restrict__ feat_r, const float* __restrict__ qe,
    const float* __restrict__ zz, const float* __restrict__ kv,
    const float* __restrict__ out_lo_w, const float* __restrict__ out_lo_b,
    const float* __restrict__ out_hi_w, const float* __restrict__ out_hi_b,
    const float* __restrict__ hp_w, const float* __restrict__ hp_b,
    const float* __restrict__ gru_wih, const float* __restrict__ gru_whh,
    const float* __restrict__ gru_bih, const float* __restrict__ gru_bhh,
    const float* __restrict__ op_w, const float* __restrict__ op_b,
    const float* __restrict__ log_decay,
    const float* __restrict__ rg1_w, const float* __restrict__ rg1_b,
    const float* __restrict__ rg2_w, const float* __restrict__ rg2_b,
    const float* __restrict__ log_reg,
    float* __restrict__ out)
{
    __shared__ float sA[32][36];
    __shared__ float sB[32][36];
    __shared__ float sC[32][36];

    const int tid = threadIdx.x;
    const int r = tid >> 3;
    const int j = tid & 7;
    const int row = blockIdx.x * 32 + r;
    const int b = __builtin_amdgcn_readfirstlane(row / cN);
    const int n = row - b * cN;

    {
        const float4* q4 = (const float4*)(qe + (size_t)row * cH);
        float4 v = q4[j];
        *(float4*)&sA[r][4 * j] = v;
    }
    __syncthreads();

    float o_m[4];
    #pragma unroll
    for (int m = 0; m < 4; ++m) {
        const float z = zz[(size_t)(b * cHEADS + m) * cN + n];
        const float* kvp = kv + (size_t)(b * cHEADS + m) * 64;
        float s = 0.0f;
        #pragma unroll
        for (int d = 0; d < 8; ++d)
            s = fmaf(sA[r][m * 8 + d], kvp[d * 8 + j], s);
        o_m[m] = s * z;
    }
    #pragma unroll
    for (int m = 0; m < 4; ++m) sB[r][m * 8 + j] = o_m[m];
    __syncthreads();

    float lo_j = out_lo_b[j];
    #pragma unroll
    for (int i = 0; i < cH; ++i)
        lo_j = fmaf(sB[r][i], out_lo_w[j * cH + i], lo_j);

    float lof[8];
    #pragma unroll
    for (int i = 0; i < 8; ++i) lof[i] = __shfl(lo_j, i, 8);

    float f2_m[4];
    #pragma unroll
    for (int m = 0; m < 4; ++m) {
        const int i = m * 8 + j;
        float s = out_hi_b[i];
        #pragma unroll
        for (int q = 0; q < 8; ++q) s = fmaf(lof[q], out_hi_w[i * 8 + q], s);
        f2_m[m] = feat_r[(size_t)row * cH + i] + s;
        sC[r][i] = f2_m[m];
    }
    __syncthreads();

    float h0_j = hp_b[j], g1_j = rg1_b[j];
    #pragma unroll
    for (int i = 0; i < cH; ++i) {
        float fv = sC[r][i];
        h0_j = fmaf(fv, hp_w[j * cH + i], h0_j);
        g1_j = fmaf(fv, rg1_w[j * cH + i], g1_j);
    }
    g1_j = fmaxf(0.0f, g1_j);

    float g1f[8];
    #pragma unroll
    for (int i = 0; i < 8; ++i) g1f[i] = __shfl(g1_j, i, 8);

    float ga = rg2_b[j], gb_ = rg2_b[8 + (j & 3)];
    #pragma unroll
    for (int q = 0; q < 8; ++q) {
        ga = fmaf(g1f[q], rg2_w[j * 8 + q], ga);
        gb_ = fmaf(g1f[q], rg2_w[(8 + (j & 3)) * 8 + q], gb_);
    }
    const float gate_a = sigmoidf_(ga);
    const float gate_b = sigmoidf_(gb_);

    const float last = x[(size_t)b * cT * cN + (size_t)(cT - 1) * cN + n];

    float whh_r[8], whh_z[8], whh_n[8], opw[8];
    #pragma unroll
    for (int i = 0; i < 8; ++i) {
        whh_r[i] = gru_whh[j * 8 + i];
        whh_z[i] = gru_whh[(8 + j) * 8 + i];
        whh_n[i] = gru_whh[(16 + j) * 8 + i];
        opw[i] = op_w[i];
    }
    const float wih_r = gru_wih[j], wih_z = gru_wih[8 + j], wih_n = gru_wih[16 + j];
    const float bih_r = gru_bih[j], bih_z = gru_bih[8 + j], bih_n = gru_bih[16 + j];
    const float bhh_r = gru_bhh[j], bhh_z = gru_bhh[8 + j], bhh_n = gru_bhh[16 + j];
    const float opb = op_b[0];

    float h_full[8];
    #pragma unroll
    for (int i = 0; i < 8; ++i) h_full[i] = __shfl(h0_j, i, 8);
    float h_own = h0_j;
    float cur = last;
    float po_a = 0.0f, po_b = 0.0f;

    #pragma unroll
    for (int s = 0; s < cHOR; ++s) {
        float ghr = bhh_r, ghz = bhh_z, ghn = bhh_n;
        #pragma unroll
        for (int i = 0; i < 8; ++i) {
            ghr = fmaf(h_full[i], whh_r[i], ghr);
            ghz = fmaf(h_full[i], whh_z[i], ghz);
            ghn = fmaf(h_full[i], whh_n[i], ghn);
        }
        const float r_ = sigmoidf_(fmaf(wih_r, cur, bih_r) + ghr);
        const float zg = sigmoidf_(fmaf(wih_z, cur, bih_z) + ghz);
        const float nn = tanhf_(fmaf(wih_n, cur, bih_n) + r_ * ghn);
        const float hn = (1.0f - zg) * nn + zg * h_own;
        h_own = hn;
        #pragma unroll
        for (int i = 0; i < 8; ++i) h_full[i] = __shfl(hn, i, 8);
        float p = opb;
        #pragma unroll
        for (int i = 0; i < 8; ++i) p = fmaf(h_full[i], opw[i], p);
        po_a = (s == j) ? p : po_a;
        po_b = (s == 8 + j) ? p : po_b;
        cur = p;
    }

    const float dk = __expf(log_decay[0]);
    float* orow = out + (size_t)row * 12;
    orow[j] = gate_a * po_a + (1.0f - gate_a) * last * __expf(-dk * (float)(j + 1));
    if (j < 4)
        orow[8 + j] = gate_b * po_b + (1.0f - gate_b) * last * __expf(-dk * (float)(j + 9));

    if (row == 0 && j == 0)
        out[(size_t)cROWS * 12] = __expf(log_reg[0]) * (1.0f / (float)cN);
}

extern "C" void kernel_launch(void* const* d_in, const int* in_sizes, int n_in,
                              void* d_out, int out_size, void* d_ws, size_t ws_size,
                              hipStream_t stream)
{
    const float* x      = (const float*)d_in[0];
    const float* dw_w   = (const float*)d_in[1];
    const float* dw_b   = (const float*)d_in[2];
    const float* bn1_g  = (const float*)d_in[3];
    const float* bn1_b  = (const float*)d_in[4];
    const float* bn1_m  = (const float*)d_in[5];
    const float* bn1_v  = (const float*)d_in[6];
    const float* pw_w   = (const float*)d_in[7];
    const float* pw_b   = (const float*)d_in[8];
    const float* bn2_g  = (const float*)d_in[9];
    const float* bn2_b  = (const float*)d_in[10];
    const float* bn2_m  = (const float*)d_in[11];
    const float* bn2_v  = (const float*)d_in[12];
    const float* fp_w   = (const float*)d_in[13];
    const float* fp_b   = (const float*)d_in[14];
    const float* lo_w   = (const float*)d_in[15];
    const float* lo_b   = (const float*)d_in[16];
    const float* hi_w   = (const float*)d_in[17];
    const float* hi_b   = (const float*)d_in[18];
    const float* olo_w  = (const float*)d_in[19];
    const float* olo_b  = (const float*)d_in[20];
    const float* ohi_w  = (const float*)d_in[21];
    const float* ohi_b  = (const float*)d_in[22];
    // d_in[23]=u, d_in[24]=v dead (softmax row-sums == 1 -> mean|attn| == 1/N)
    const float* log_reg = (const float*)d_in[25];
    const float* hp_w   = (const float*)d_in[26];
    const float* hp_b   = (const float*)d_in[27];
    const float* gru_wih = (const float*)d_in[28];
    const float* gru_whh = (const float*)d_in[29];
    const float* gru_bih = (const float*)d_in[30];
    const float* gru_bhh = (const float*)d_in[31];
    const float* op_w   = (const float*)d_in[32];
    const float* op_b   = (const float*)d_in[33];
    const float* log_decay = (const float*)d_in[34];
    const float* rg1_w  = (const float*)d_in[35];
    const float* rg1_b  = (const float*)d_in[36];
    const float* rg2_w  = (const float*)d_in[37];
    const float* rg2_b  = (const float*)d_in[38];

    float* ws     = (float*)d_ws;
    float* wT     = ws;                    // 32768
    float* feat_r = wT + 32768;            // 409600  [row*32+h]
    float* qe     = feat_r + 409600;       // 409600  [row*32]
    float* zz     = qe + 409600;           // 51200   [(b*4+h)*1600+n]
    float* kv     = zz + 51200;            // 2048

    k0_init<<<128, 256, 0, stream>>>(fp_w, wT, kv);
    kA<<<cROWS / 64, 1024, 0, stream>>>(x, dw_w, dw_b, bn1_g, bn1_b, bn1_m, bn1_v,
                                        pw_w, pw_b, bn2_g, bn2_b, bn2_m, bn2_v,
                                        wT, fp_b, lo_w, lo_b, hi_w, hi_b,
                                        feat_r, qe, zz, kv);
    k4_final<<<cROWS / 32, 256, 0, stream>>>(x, feat_r, qe, zz, kv,
                                             olo_w, olo_b, ohi_w, ohi_b,
                                             hp_w, hp_b, gru_wih, gru_whh, gru_bih, gru_bhh,
                                             op_w, op_b, log_decay,
                                             rg1_w, rg1_b, rg2_w, rg2_b, log_reg,
                                             (float*)d_out);
}